// Round 3
// baseline (818.808 us; speedup 1.0000x reference)
//
#include <hip/hip_runtime.h>

// 2-layer GCN, gather formulation via device-built CSR:
//   dinv = rsqrt(1 + indeg)
//   g1 = dinv * (x @ W1)        -- bf16-split MFMA (hi*hi + lo*hi + hi*lo)
//   row(v) = relu(b1 + dinv[v]*(g1[v] + sum_{in} g1[src]))
//   g2[v] = dinv[v] * (row(v) @ W2)           (fused into gather1 kernel)
//   out[v] = b2 + dinv[v]*(g2[v] + sum_{in} g2[src])

constexpr int C1 = 64;
constexpr int C2 = 32;
constexpr int K1 = 768;
constexpr int SCAN_BS = 256;
constexpr int SCAN_ELEMS = 2048;   // 8 per thread

typedef __attribute__((ext_vector_type(8))) short short8;
typedef __attribute__((ext_vector_type(4))) float floatx4;

// ---------- edge dtype detection (device-side, graph-capture safe) ----------
__global__ void detect_k(const int* __restrict__ ei32, int* flag, int n_words) {
    __shared__ int any_nz;
    if (threadIdx.x == 0) any_nz = 0;
    __syncthreads();
    int w = 2 * threadIdx.x + 1;     // odd words = high halves if int64
    if (w < n_words && ei32[w] != 0) atomicOr(&any_nz, 1);
    __syncthreads();
    if (threadIdx.x == 0) *flag = (any_nz == 0) ? 1 : 0;
}

__device__ __forceinline__ int load_idx(const void* ei, size_t pos, int m64) {
    if (m64) return (int)((const long long*)ei)[pos];
    return ((const int*)ei)[pos];
}

// ---------- degree ----------
__global__ void zero_k(int* p, int n) {
    int i = blockIdx.x * 256 + threadIdx.x;
    if (i < n) p[i] = 0;
}

__global__ void cnt_k(const void* __restrict__ ei, const int* __restrict__ flag,
                      int* cnt, int E) {
    int e = blockIdx.x * 256 + threadIdx.x;
    if (e >= E) return;
    int m64 = *flag;
    int d = load_idx(ei, (size_t)E + e, m64);
    atomicAdd(&cnt[d], 1);
}

__global__ void dinv_k(const int* __restrict__ cnt, float* dinv, int n) {
    int i = blockIdx.x * 256 + threadIdx.x;
    if (i < n) dinv[i] = rsqrtf(1.0f + (float)cnt[i]);   // +1 self-loop
}

// ---------- block scan (exclusive) over cnt -> offsets, cursor ----------
__global__ void scan1_k(const int* __restrict__ cnt, int* partials, int n) {
    __shared__ int s[SCAN_BS];
    int base = blockIdx.x * SCAN_ELEMS;
    int t = threadIdx.x;
    int sum = 0;
    #pragma unroll
    for (int i = 0; i < 8; ++i) {
        int idx = base + t * 8 + i;
        if (idx < n) sum += cnt[idx];
    }
    s[t] = sum;
    __syncthreads();
    for (int off = 128; off > 0; off >>= 1) {
        if (t < off) s[t] += s[t + off];
        __syncthreads();
    }
    if (t == 0) partials[blockIdx.x] = s[0];
}

__global__ void scan2_k(int* partials, int* total_out, int nb) {
    __shared__ int s[256];
    int t = threadIdx.x;
    int v = (t < nb) ? partials[t] : 0;
    s[t] = v;
    __syncthreads();
    for (int off = 1; off < 256; off <<= 1) {
        int add = (t >= off) ? s[t - off] : 0;
        __syncthreads();
        s[t] += add;
        __syncthreads();
    }
    if (t < nb) partials[t] = s[t] - v;     // exclusive block offsets
    if (t == 0) *total_out = s[255];        // offsets[n]
}

__global__ void scan3_k(const int* __restrict__ cnt, const int* __restrict__ partials,
                        int* offsets, int* cursor, int n) {
    __shared__ int s[SCAN_BS];
    int base = blockIdx.x * SCAN_ELEMS;
    int t = threadIdx.x;
    int local[8];
    int sum = 0;
    #pragma unroll
    for (int i = 0; i < 8; ++i) {
        int idx = base + t * 8 + i;
        int v = (idx < n) ? cnt[idx] : 0;
        local[i] = sum;
        sum += v;
    }
    int mine = sum;
    s[t] = sum;
    __syncthreads();
    for (int off = 1; off < 256; off <<= 1) {
        int add = (t >= off) ? s[t - off] : 0;
        __syncthreads();
        s[t] += add;
        __syncthreads();
    }
    int texcl = s[t] - mine;
    int boff = partials[blockIdx.x];
    #pragma unroll
    for (int i = 0; i < 8; ++i) {
        int idx = base + t * 8 + i;
        if (idx < n) {
            int o = boff + texcl + local[i];
            offsets[idx] = o;
            cursor[idx] = o;
        }
    }
}

// ---------- CSR fill ----------
__global__ void fill_k(const void* __restrict__ ei, const int* __restrict__ flag,
                       int* cursor, int* adj, int E) {
    int e = blockIdx.x * 256 + threadIdx.x;
    if (e >= E) return;
    int m64 = *flag;
    int s = load_idx(ei, e, m64);
    int d = load_idx(ei, (size_t)E + e, m64);
    int pos = atomicAdd(&cursor[d], 1);
    adj[pos] = s;
}

// ---------- bf16 split: RNE hi + exact sub + chop lo (same numerics as R1/R2) ----
__device__ __forceinline__ void bf16_split(float f, short& hi, short& lo) {
    unsigned int u = __float_as_uint(f);
    unsigned int r = u + (0x7FFFu + ((u >> 16) & 1u));   // RNE in top 16 bits
    hi = (short)(r >> 16);
    float rem = f - __uint_as_float(r & 0xFFFF0000u);    // exact
    lo = (short)(__float_as_uint(rem) >> 16);            // chop (residual ~2^-16|f|)
}

__device__ __forceinline__ void split8(const float4& a, const float4& b,
                                       short8& h, short8& v) {
    float f[8] = {a.x, a.y, a.z, a.w, b.x, b.y, b.z, b.w};
    #pragma unroll
    for (int j = 0; j < 8; ++j) {
        short hh, ll;
        bf16_split(f[j], hh, ll);
        h[j] = hh;
        v[j] = ll;
    }
}

// ---------- pack W1 into per-lane MFMA B-fragments (hi/lo planes) ----------
// Fragment (s,t,p): k-step s (32 k), col-tile t (16 cols), plane p (0=hi,1=lo).
// Lane l holds col = 16t + (l&15), k = 32s + 8*(l>>4) + j, j=0..7.
// Layout: Bp[ fi*512 + l*8 + j ] ushorts, fi = (s*4 + t)*2 + p.
// Step s occupies a contiguous 8 KB slab Bp[s*4096 .. s*4096+4095].
__global__ void packW1_k(const float* __restrict__ W1, unsigned short* __restrict__ Bp) {
    int gid = blockIdx.x * 256 + threadIdx.x;
    if (gid >= 24 * 4 * 2 * 64) return;
    int l    = gid & 63;
    int frag = gid >> 6;
    int p = frag & 1;
    int t = (frag >> 1) & 3;
    int s = frag >> 3;
    int c = t * 16 + (l & 15);
    int kbase = s * 32 + (l >> 4) * 8;
    short8 v;
    #pragma unroll
    for (int j = 0; j < 8; ++j) {
        short hi, lo;
        bf16_split(W1[(size_t)(kbase + j) * C1 + c], hi, lo);
        v[j] = p ? lo : hi;
    }
    *(short8*)(Bp + (size_t)gid * 8) = v;
}

// ---------- GEMM1 (MFMA, bf16-split, NO LDS / NO BARRIERS) ----------
// 128 rows/block, 4 waves; wave w owns rows [w*32, w*32+32) as two 16-row A-frags.
// A fragments load DIRECTLY global->VGPR (lanes {l,l+16,l+32,l+48} cover one
// row's 128B contiguously => full coalescing). B fragments are 1KB coalesced
// loads from packed L2-resident Bp. Register-level 1-deep A prefetch; waves
// run fully independently (latency hidden by TLP + compiler load hoisting).
__global__ __launch_bounds__(256, 3) void gemm1_k(const float* __restrict__ x,
                                                  const unsigned short* __restrict__ Bp,
                                                  const float* __restrict__ dinv,
                                                  float* __restrict__ g1, int n) {
    const int tid = threadIdx.x;
    const int w = tid >> 6;                 // wave 0..3
    const int l = tid & 63;                 // lane
    const int block_row = blockIdx.x * 128;
    const int wrow = block_row + w * 32;

    int row0 = wrow + (l & 15);        if (row0 > n - 1) row0 = n - 1;
    int row1 = wrow + 16 + (l & 15);   if (row1 > n - 1) row1 = n - 1;
    const int kl = (l >> 4) * 8;            // lane's k-offset within a 32-wide step

    const float* __restrict__ pa0 = x + (size_t)row0 * K1 + kl;
    const float* __restrict__ pa1 = x + (size_t)row1 * K1 + kl;
    const unsigned short* __restrict__ pb = Bp + l * 8;

    floatx4 zero = {0.f, 0.f, 0.f, 0.f};
    floatx4 acc[2][4];
    #pragma unroll
    for (int r = 0; r < 2; ++r)
        #pragma unroll
        for (int t = 0; t < 4; ++t) acc[r][t] = zero;

    // prefetch A for step 0
    float4 a0a = *(const float4*)(pa0 + 0);
    float4 a0b = *(const float4*)(pa0 + 4);
    float4 a1a = *(const float4*)(pa1 + 0);
    float4 a1b = *(const float4*)(pa1 + 4);

    for (int t = 0; t < 24; ++t) {
        // ---- issue next-step A prefetch first (HBM latency hides under body) --
        const int tn = (t + 1 < 24) ? (t + 1) * 32 : 0;     // tail: harmless re-read
        float4 n0a = *(const float4*)(pa0 + tn);
        float4 n0b = *(const float4*)(pa0 + tn + 4);
        float4 n1a = *(const float4*)(pa1 + tn);
        float4 n1b = *(const float4*)(pa1 + tn + 4);

        // ---- B fragments for step t (L2-resident, 1KB coalesced each) ----
        const unsigned short* bt = pb + t * 4096;
        short8 bh[4], bl[4];
        #pragma unroll
        for (int tt = 0; tt < 4; ++tt) {
            bh[tt] = *(const short8*)(bt + (tt * 2 + 0) * 512);
            bl[tt] = *(const short8*)(bt + (tt * 2 + 1) * 512);
        }

        // ---- split current A (registers only; covers B load latency) ----
        short8 ah0, al0, ah1, al1;
        split8(a0a, a0b, ah0, al0);
        split8(a1a, a1b, ah1, al1);

        // ---- 24 MFMA: 2 frags x 4 col-tiles x 3 planes ----
        #pragma unroll
        for (int tt = 0; tt < 4; ++tt) {
            acc[0][tt] = __builtin_amdgcn_mfma_f32_16x16x32_bf16(ah0, bl[tt], acc[0][tt], 0, 0, 0);
            acc[0][tt] = __builtin_amdgcn_mfma_f32_16x16x32_bf16(al0, bh[tt], acc[0][tt], 0, 0, 0);
            acc[0][tt] = __builtin_amdgcn_mfma_f32_16x16x32_bf16(ah0, bh[tt], acc[0][tt], 0, 0, 0);
            acc[1][tt] = __builtin_amdgcn_mfma_f32_16x16x32_bf16(ah1, bl[tt], acc[1][tt], 0, 0, 0);
            acc[1][tt] = __builtin_amdgcn_mfma_f32_16x16x32_bf16(al1, bh[tt], acc[1][tt], 0, 0, 0);
            acc[1][tt] = __builtin_amdgcn_mfma_f32_16x16x32_bf16(ah1, bh[tt], acc[1][tt], 0, 0, 0);
        }

        // ---- rotate prefetch ----
        a0a = n0a; a0b = n0b; a1a = n1a; a1b = n1b;
    }

    // ---- epilogue: C/D map col=lane&15, row=(lane>>4)*4+i (m89-verified) ----
    #pragma unroll
    for (int r = 0; r < 2; ++r) {
        #pragma unroll
        for (int i = 0; i < 4; ++i) {
            int row = block_row + w * 32 + r * 16 + (l >> 4) * 4 + i;
            if (row < n) {
                float dv = dinv[row];
                #pragma unroll
                for (int t = 0; t < 4; ++t) {
                    g1[(size_t)row * C1 + t * 16 + (l & 15)] = acc[r][t][i] * dv;
                }
            }
        }
    }
}

// ---------- layer-1 gather + fused GEMM2 ----------
// one wave per node (lane = channel). After gathering the 64-wide row,
// the wave computes h2 = relu(row)@W2 via LDS and writes g2 = dinv*h2.
__global__ __launch_bounds__(256) void gather1_k(const int* __restrict__ offsets,
                                                 const int* __restrict__ adj,
                                                 const float* __restrict__ dinv,
                                                 const float* __restrict__ g1,
                                                 const float* __restrict__ b1,
                                                 const float* __restrict__ W2,
                                                 float* __restrict__ g2, int n) {
    __shared__ float sW[C1 * C2];    // 8 KB
    __shared__ float srow[4][C1];
    const int tid = threadIdx.x;
    for (int i = tid; i < C1 * C2; i += 256) sW[i] = W2[i];

    const int wid = tid >> 6;
    const int c = tid & 63;
    const int v = blockIdx.x * 4 + wid;

    float r = 0.f;
    float dv = 0.f;
    if (v < n) {
        dv = dinv[v];
        int start = offsets[v], end = offsets[v + 1];
        float acc = g1[(size_t)v * C1 + c];          // self-loop term
        int j = start;
        for (; j + 4 <= end; j += 4) {
            int s0 = adj[j], s1 = adj[j + 1], s2 = adj[j + 2], s3 = adj[j + 3];
            float a0 = g1[(size_t)s0 * C1 + c];
            float a1 = g1[(size_t)s1 * C1 + c];
            float a2 = g1[(size_t)s2 * C1 + c];
            float a3 = g1[(size_t)s3 * C1 + c];
            acc += (a0 + a1) + (a2 + a3);
        }
        for (; j < end; ++j) acc += g1[(size_t)adj[j] * C1 + c];
        r = fmaxf(b1[c] + dv * acc, 0.f);            // fused bias + relu
    }
    srow[wid][c] = r;
    __syncthreads();                                  // covers sW + srow

    if (v < n && c < C2) {
        float acc = 0.f;
        #pragma unroll
        for (int k = 0; k < C1; ++k) acc += srow[wid][k] * sW[k * C2 + c];
        g2[(size_t)v * C2 + c] = dv * acc;
    }
}

// ---------- layer-2 gather (2 nodes per wave, 32 lanes each) ----------
__global__ __launch_bounds__(256) void gather2_k(const int* __restrict__ offsets,
                                                 const int* __restrict__ adj,
                                                 const float* __restrict__ dinv,
                                                 const float* __restrict__ g2,
                                                 const float* __restrict__ b2,
                                                 float* __restrict__ out, int n) {
    int v = blockIdx.x * 8 + (threadIdx.x >> 5);
    int c = threadIdx.x & 31;
    if (v >= n) return;
    int start = offsets[v], end = offsets[v + 1];
    float acc = g2[(size_t)v * C2 + c];              // self-loop term
    int j = start;
    for (; j + 4 <= end; j += 4) {
        int s0 = adj[j], s1 = adj[j + 1], s2 = adj[j + 2], s3 = adj[j + 3];
        float a0 = g2[(size_t)s0 * C2 + c];
        float a1 = g2[(size_t)s1 * C2 + c];
        float a2 = g2[(size_t)s2 * C2 + c];
        float a3 = g2[(size_t)s3 * C2 + c];
        acc += (a0 + a1) + (a2 + a3);
    }
    for (; j < end; ++j) acc += g2[(size_t)adj[j] * C2 + c];
    out[(size_t)v * C2 + c] = b2[c] + dinv[v] * acc;
}

extern "C" void kernel_launch(void* const* d_in, const int* in_sizes, int n_in,
                              void* d_out, int out_size, void* d_ws, size_t ws_size,
                              hipStream_t stream) {
    const float* x  = (const float*)d_in[0];
    const void*  ei = d_in[1];
    const float* W1 = (const float*)d_in[2];
    const float* b1 = (const float*)d_in[3];
    const float* W2 = (const float*)d_in[4];
    const float* b2 = (const float*)d_in[5];
    float* out = (float*)d_out;

    const int n = in_sizes[0] / K1;     // 100000
    const int E = in_sizes[1] / 2;      // 1600000

    // workspace layout (all 4-byte types)
    float* ws      = (float*)d_ws;
    int*   flag    = (int*)ws;                      // 16-float header
    float* dinv    = ws + 16;                       // n
    float* g1      = dinv + n;                      // n*64
    float* g2      = g1 + (size_t)n * C1;           // n*32
    int*   cnt     = (int*)(g2 + (size_t)n * C2);   // n
    int*   offsets = cnt + n;                       // n+1
    int*   cursor  = offsets + n + 1;               // n
    int*   partials= cursor + n;                    // 256 (padded)
    int*   adj     = partials + 256;                // E
    uintptr_t bp_a = ((uintptr_t)(adj + E) + 15) & ~(uintptr_t)15;
    unsigned short* Bp = (unsigned short*)bp_a;     // 192 KB packed W1 fragments

    const int nb_scan = (n + SCAN_ELEMS - 1) / SCAN_ELEMS;   // 49

    detect_k<<<1, 256, 0, stream>>>((const int*)ei, flag, in_sizes[1]);
    zero_k<<<(n + 255) / 256, 256, 0, stream>>>(cnt, n);
    cnt_k<<<(E + 255) / 256, 256, 0, stream>>>(ei, flag, cnt, E);
    dinv_k<<<(n + 255) / 256, 256, 0, stream>>>(cnt, dinv, n);

    packW1_k<<<48, 256, 0, stream>>>(W1, Bp);
    gemm1_k<<<(n + 127) / 128, 256, 0, stream>>>(x, Bp, dinv, g1, n);

    scan1_k<<<nb_scan, SCAN_BS, 0, stream>>>(cnt, partials, n);
    scan2_k<<<1, 256, 0, stream>>>(partials, offsets + n, nb_scan);
    scan3_k<<<nb_scan, SCAN_BS, 0, stream>>>(cnt, partials, offsets, cursor, n);
    fill_k<<<(E + 255) / 256, 256, 0, stream>>>(ei, flag, cursor, adj, E);

    gather1_k<<<(n + 3) / 4, 256, 0, stream>>>(offsets, adj, dinv, g1, b1, W2, g2, n);
    gather2_k<<<(n + 7) / 8, 256, 0, stream>>>(offsets, adj, dinv, g2, b2, out, n);
}

// Round 4
// 791.856 us; speedup vs baseline: 1.0340x; 1.0340x over previous
//
#include <hip/hip_runtime.h>

// 2-layer GCN, gather formulation via device-built CSR:
//   dinv = rsqrt(1 + indeg)
//   g1 = dinv * (x @ W1)        -- bf16-split MFMA (hi*hi + lo*hi + hi*lo)
//   row(v) = relu(b1 + dinv[v]*(g1[v] + sum_{in} g1[src]))
//   g2[v] = dinv[v] * (row(v) @ W2)           (fused into gather1 kernel)
//   out[v] = b2 + dinv[v]*(g2[v] + sum_{in} g2[src])

constexpr int C1 = 64;
constexpr int C2 = 32;
constexpr int K1 = 768;
constexpr int SCAN_BS = 256;
constexpr int SCAN_ELEMS = 2048;   // 8 per thread

typedef __attribute__((ext_vector_type(8))) short short8;
typedef __attribute__((ext_vector_type(4))) float floatx4;

// ---------- edge dtype detection (device-side, graph-capture safe) ----------
__global__ void detect_k(const int* __restrict__ ei32, int* flag, int n_words) {
    __shared__ int any_nz;
    if (threadIdx.x == 0) any_nz = 0;
    __syncthreads();
    int w = 2 * threadIdx.x + 1;     // odd words = high halves if int64
    if (w < n_words && ei32[w] != 0) atomicOr(&any_nz, 1);
    __syncthreads();
    if (threadIdx.x == 0) *flag = (any_nz == 0) ? 1 : 0;
}

__device__ __forceinline__ int load_idx(const void* ei, size_t pos, int m64) {
    if (m64) return (int)((const long long*)ei)[pos];
    return ((const int*)ei)[pos];
}

// ---------- degree ----------
__global__ void zero_k(int* p, int n) {
    int i = blockIdx.x * 256 + threadIdx.x;
    if (i < n) p[i] = 0;
}

__global__ void cnt_k(const void* __restrict__ ei, const int* __restrict__ flag,
                      int* cnt, int E) {
    int e = blockIdx.x * 256 + threadIdx.x;
    if (e >= E) return;
    int m64 = *flag;
    int d = load_idx(ei, (size_t)E + e, m64);
    atomicAdd(&cnt[d], 1);
}

__global__ void dinv_k(const int* __restrict__ cnt, float* dinv, int n) {
    int i = blockIdx.x * 256 + threadIdx.x;
    if (i < n) dinv[i] = rsqrtf(1.0f + (float)cnt[i]);   // +1 self-loop
}

// ---------- block scan (exclusive) over cnt -> offsets, cursor ----------
__global__ void scan1_k(const int* __restrict__ cnt, int* partials, int n) {
    __shared__ int s[SCAN_BS];
    int base = blockIdx.x * SCAN_ELEMS;
    int t = threadIdx.x;
    int sum = 0;
    #pragma unroll
    for (int i = 0; i < 8; ++i) {
        int idx = base + t * 8 + i;
        if (idx < n) sum += cnt[idx];
    }
    s[t] = sum;
    __syncthreads();
    for (int off = 128; off > 0; off >>= 1) {
        if (t < off) s[t] += s[t + off];
        __syncthreads();
    }
    if (t == 0) partials[blockIdx.x] = s[0];
}

__global__ void scan2_k(int* partials, int* total_out, int nb) {
    __shared__ int s[256];
    int t = threadIdx.x;
    int v = (t < nb) ? partials[t] : 0;
    s[t] = v;
    __syncthreads();
    for (int off = 1; off < 256; off <<= 1) {
        int add = (t >= off) ? s[t - off] : 0;
        __syncthreads();
        s[t] += add;
        __syncthreads();
    }
    if (t < nb) partials[t] = s[t] - v;     // exclusive block offsets
    if (t == 0) *total_out = s[255];        // offsets[n]
}

__global__ void scan3_k(const int* __restrict__ cnt, const int* __restrict__ partials,
                        int* offsets, int* cursor, int n) {
    __shared__ int s[SCAN_BS];
    int base = blockIdx.x * SCAN_ELEMS;
    int t = threadIdx.x;
    int local[8];
    int sum = 0;
    #pragma unroll
    for (int i = 0; i < 8; ++i) {
        int idx = base + t * 8 + i;
        int v = (idx < n) ? cnt[idx] : 0;
        local[i] = sum;
        sum += v;
    }
    int mine = sum;
    s[t] = sum;
    __syncthreads();
    for (int off = 1; off < 256; off <<= 1) {
        int add = (t >= off) ? s[t - off] : 0;
        __syncthreads();
        s[t] += add;
        __syncthreads();
    }
    int texcl = s[t] - mine;
    int boff = partials[blockIdx.x];
    #pragma unroll
    for (int i = 0; i < 8; ++i) {
        int idx = base + t * 8 + i;
        if (idx < n) {
            int o = boff + texcl + local[i];
            offsets[idx] = o;
            cursor[idx] = o;
        }
    }
}

// ---------- CSR fill ----------
__global__ void fill_k(const void* __restrict__ ei, const int* __restrict__ flag,
                       int* cursor, int* adj, int E) {
    int e = blockIdx.x * 256 + threadIdx.x;
    if (e >= E) return;
    int m64 = *flag;
    int s = load_idx(ei, e, m64);
    int d = load_idx(ei, (size_t)E + e, m64);
    int pos = atomicAdd(&cursor[d], 1);
    adj[pos] = s;
}

// ---------- bf16 split: RNE hi + exact sub + chop lo (same numerics as R1-R3) ----
__device__ __forceinline__ void bf16_split(float f, short& hi, short& lo) {
    unsigned int u = __float_as_uint(f);
    unsigned int r = u + (0x7FFFu + ((u >> 16) & 1u));   // RNE in top 16 bits
    hi = (short)(r >> 16);
    float rem = f - __uint_as_float(r & 0xFFFF0000u);    // exact
    lo = (short)(__float_as_uint(rem) >> 16);            // chop (residual ~2^-16|f|)
}

__device__ __forceinline__ void split8(const float4& a, const float4& b,
                                       short8& h, short8& v) {
    float f[8] = {a.x, a.y, a.z, a.w, b.x, b.y, b.z, b.w};
    #pragma unroll
    for (int j = 0; j < 8; ++j) {
        short hh, ll;
        bf16_split(f[j], hh, ll);
        h[j] = hh;
        v[j] = ll;
    }
}

// ---------- pack W1 into per-lane MFMA B-fragments (hi/lo planes) ----------
// Fragment (s,t,p): k-step s (32 k), col-tile t (16 cols), plane p (0=hi,1=lo).
// Lane l holds col = 16t + (l&15), k = 32s + 8*(l>>4) + j, j=0..7.
// Layout: Bp[ fi*512 + l*8 + j ] ushorts, fi = (s*4 + t)*2 + p.
// Step s occupies a contiguous 8 KB slab Bp[s*4096 .. s*4096+4095].
__global__ void packW1_k(const float* __restrict__ W1, unsigned short* __restrict__ Bp) {
    int gid = blockIdx.x * 256 + threadIdx.x;
    if (gid >= 24 * 4 * 2 * 64) return;
    int l    = gid & 63;
    int frag = gid >> 6;
    int p = frag & 1;
    int t = (frag >> 1) & 3;
    int s = frag >> 3;
    int c = t * 16 + (l & 15);
    int kbase = s * 32 + (l >> 4) * 8;
    short8 v;
    #pragma unroll
    for (int j = 0; j < 8; ++j) {
        short hi, lo;
        bf16_split(W1[(size_t)(kbase + j) * C1 + c], hi, lo);
        v[j] = p ? lo : hi;
    }
    *(short8*)(Bp + (size_t)gid * 8) = v;
}

// ---------- GEMM1 (MFMA, bf16-split, no LDS, 64-wide K-steps) ----------
// 128 rows/block, 4 waves; wave w owns rows [w*32, w*32+32) as two 16-row A-frags.
// A loads DIRECTLY global->VGPR (lanes {l,l+16,l+32,l+48} cover one row's 128B
// contiguously => full coalescing). K processed in 12 iterations of 64; the
// ENTIRE next 64-step (8 float4/thread) prefetched at the top of each iteration
// -> ~640 cyc of body x 3 waves/SIMD covers the ~900 cyc HBM latency.
__global__ __launch_bounds__(256, 3) void gemm1_k(const float* __restrict__ x,
                                                  const unsigned short* __restrict__ Bp,
                                                  const float* __restrict__ dinv,
                                                  float* __restrict__ g1, int n) {
    const int tid = threadIdx.x;
    const int w = tid >> 6;                 // wave 0..3
    const int l = tid & 63;                 // lane
    const int block_row = blockIdx.x * 128;
    const int wrow = block_row + w * 32;

    int row0 = wrow + (l & 15);        if (row0 > n - 1) row0 = n - 1;
    int row1 = wrow + 16 + (l & 15);   if (row1 > n - 1) row1 = n - 1;
    const int kl = (l >> 4) * 8;            // lane's k-offset within a 32-wide step

    const float* __restrict__ pa0 = x + (size_t)row0 * K1 + kl;
    const float* __restrict__ pa1 = x + (size_t)row1 * K1 + kl;
    const unsigned short* __restrict__ pb = Bp + l * 8;

    floatx4 zero = {0.f, 0.f, 0.f, 0.f};
    floatx4 acc[2][4];
    #pragma unroll
    for (int r = 0; r < 2; ++r)
        #pragma unroll
        for (int t = 0; t < 4; ++t) acc[r][t] = zero;

    // current 64-step A (named regs; no runtime-indexed arrays)
    float4 c00 = *(const float4*)(pa0 + 0);
    float4 c01 = *(const float4*)(pa0 + 4);
    float4 c02 = *(const float4*)(pa0 + 32);
    float4 c03 = *(const float4*)(pa0 + 36);
    float4 c10 = *(const float4*)(pa1 + 0);
    float4 c11 = *(const float4*)(pa1 + 4);
    float4 c12 = *(const float4*)(pa1 + 32);
    float4 c13 = *(const float4*)(pa1 + 36);

    for (int t = 0; t < 12; ++t) {
        // ---- prefetch next 64-step (tail: harmless re-read of step 0) ----
        const int kn = (t + 1 < 12) ? (t + 1) * 64 : 0;
        float4 m00 = *(const float4*)(pa0 + kn + 0);
        float4 m01 = *(const float4*)(pa0 + kn + 4);
        float4 m02 = *(const float4*)(pa0 + kn + 32);
        float4 m03 = *(const float4*)(pa0 + kn + 36);
        float4 m10 = *(const float4*)(pa1 + kn + 0);
        float4 m11 = *(const float4*)(pa1 + kn + 4);
        float4 m12 = *(const float4*)(pa1 + kn + 32);
        float4 m13 = *(const float4*)(pa1 + kn + 36);

        short8 bh[4], bl[4];
        short8 ah0, al0, ah1, al1;

        // ---- substep 0: 32-step index 2t ----
        {
            const unsigned short* bt = pb + (size_t)(2 * t) * 4096;
            #pragma unroll
            for (int tt = 0; tt < 4; ++tt) {
                bh[tt] = *(const short8*)(bt + (tt * 2 + 0) * 512);
                bl[tt] = *(const short8*)(bt + (tt * 2 + 1) * 512);
            }
            split8(c00, c01, ah0, al0);
            split8(c10, c11, ah1, al1);
            #pragma unroll
            for (int tt = 0; tt < 4; ++tt) {
                acc[0][tt] = __builtin_amdgcn_mfma_f32_16x16x32_bf16(ah0, bl[tt], acc[0][tt], 0, 0, 0);
                acc[0][tt] = __builtin_amdgcn_mfma_f32_16x16x32_bf16(al0, bh[tt], acc[0][tt], 0, 0, 0);
                acc[0][tt] = __builtin_amdgcn_mfma_f32_16x16x32_bf16(ah0, bh[tt], acc[0][tt], 0, 0, 0);
                acc[1][tt] = __builtin_amdgcn_mfma_f32_16x16x32_bf16(ah1, bl[tt], acc[1][tt], 0, 0, 0);
                acc[1][tt] = __builtin_amdgcn_mfma_f32_16x16x32_bf16(al1, bh[tt], acc[1][tt], 0, 0, 0);
                acc[1][tt] = __builtin_amdgcn_mfma_f32_16x16x32_bf16(ah1, bh[tt], acc[1][tt], 0, 0, 0);
            }
        }
        // ---- substep 1: 32-step index 2t+1 ----
        {
            const unsigned short* bt = pb + (size_t)(2 * t + 1) * 4096;
            #pragma unroll
            for (int tt = 0; tt < 4; ++tt) {
                bh[tt] = *(const short8*)(bt + (tt * 2 + 0) * 512);
                bl[tt] = *(const short8*)(bt + (tt * 2 + 1) * 512);
            }
            split8(c02, c03, ah0, al0);
            split8(c12, c13, ah1, al1);
            #pragma unroll
            for (int tt = 0; tt < 4; ++tt) {
                acc[0][tt] = __builtin_amdgcn_mfma_f32_16x16x32_bf16(ah0, bl[tt], acc[0][tt], 0, 0, 0);
                acc[0][tt] = __builtin_amdgcn_mfma_f32_16x16x32_bf16(al0, bh[tt], acc[0][tt], 0, 0, 0);
                acc[0][tt] = __builtin_amdgcn_mfma_f32_16x16x32_bf16(ah0, bh[tt], acc[0][tt], 0, 0, 0);
                acc[1][tt] = __builtin_amdgcn_mfma_f32_16x16x32_bf16(ah1, bl[tt], acc[1][tt], 0, 0, 0);
                acc[1][tt] = __builtin_amdgcn_mfma_f32_16x16x32_bf16(al1, bh[tt], acc[1][tt], 0, 0, 0);
                acc[1][tt] = __builtin_amdgcn_mfma_f32_16x16x32_bf16(ah1, bh[tt], acc[1][tt], 0, 0, 0);
            }
        }

        // ---- rotate prefetch ----
        c00 = m00; c01 = m01; c02 = m02; c03 = m03;
        c10 = m10; c11 = m11; c12 = m12; c13 = m13;
    }

    // ---- epilogue: C/D map col=lane&15, row=(lane>>4)*4+i (m89-verified) ----
    #pragma unroll
    for (int r = 0; r < 2; ++r) {
        #pragma unroll
        for (int i = 0; i < 4; ++i) {
            int row = block_row + w * 32 + r * 16 + (l >> 4) * 4 + i;
            if (row < n) {
                float dv = dinv[row];
                #pragma unroll
                for (int t = 0; t < 4; ++t) {
                    g1[(size_t)row * C1 + t * 16 + (l & 15)] = acc[r][t][i] * dv;
                }
            }
        }
    }
}

// ---------- layer-1 gather + fused GEMM2 (float4 lanes: 4 nodes/wave) ----------
// 16-lane group per node, lane covers 4 channels (float4). 16 nodes per block.
// 4x the independent gather chains per wave vs lane=channel (latency hiding).
__global__ __launch_bounds__(256) void gather1_k(const int* __restrict__ offsets,
                                                 const int* __restrict__ adj,
                                                 const float* __restrict__ dinv,
                                                 const float* __restrict__ g1,
                                                 const float* __restrict__ b1,
                                                 const float* __restrict__ W2,
                                                 float* __restrict__ g2, int n) {
    __shared__ float sW[C1 * C2];     // 8 KB
    __shared__ float srow[16][C1];    // 4 KB
    __shared__ float sdv[16];
    const int tid = threadIdx.x;
    for (int i = tid; i < C1 * C2; i += 256) sW[i] = W2[i];

    const int wid  = tid >> 6;
    const int l    = tid & 63;
    const int grp  = l >> 4;                 // node-group within wave (0..3)
    const int lc   = l & 15;                 // lane within group
    const int slot = wid * 4 + grp;          // 0..15
    const int v    = blockIdx.x * 16 + slot;
    const int c0   = lc * 4;                 // channel quad

    float4 acc = make_float4(0.f, 0.f, 0.f, 0.f);
    float dv = 0.f;
    if (v < n) {
        dv = dinv[v];
        acc = *(const float4*)(g1 + (size_t)v * C1 + c0);      // self-loop term
        int start = offsets[v], end = offsets[v + 1];
        int j = start;
        for (; j + 4 <= end; j += 4) {
            int s0 = adj[j], s1 = adj[j + 1], s2 = adj[j + 2], s3 = adj[j + 3];
            float4 a0 = *(const float4*)(g1 + (size_t)s0 * C1 + c0);
            float4 a1 = *(const float4*)(g1 + (size_t)s1 * C1 + c0);
            float4 a2 = *(const float4*)(g1 + (size_t)s2 * C1 + c0);
            float4 a3 = *(const float4*)(g1 + (size_t)s3 * C1 + c0);
            acc.x += (a0.x + a1.x) + (a2.x + a3.x);
            acc.y += (a0.y + a1.y) + (a2.y + a3.y);
            acc.z += (a0.z + a1.z) + (a2.z + a3.z);
            acc.w += (a0.w + a1.w) + (a2.w + a3.w);
        }
        for (; j < end; ++j) {
            float4 a = *(const float4*)(g1 + (size_t)adj[j] * C1 + c0);
            acc.x += a.x; acc.y += a.y; acc.z += a.z; acc.w += a.w;
        }
        float4 bb = *(const float4*)(b1 + c0);
        acc.x = fmaxf(bb.x + dv * acc.x, 0.f);    // fused bias + relu
        acc.y = fmaxf(bb.y + dv * acc.y, 0.f);
        acc.z = fmaxf(bb.z + dv * acc.z, 0.f);
        acc.w = fmaxf(bb.w + dv * acc.w, 0.f);
    }
    srow[slot][c0 + 0] = acc.x;
    srow[slot][c0 + 1] = acc.y;
    srow[slot][c0 + 2] = acc.z;
    srow[slot][c0 + 3] = acc.w;
    if (lc == 0) sdv[slot] = dv;
    __syncthreads();                                  // covers sW + srow + sdv

    // GEMM2: 16 nodes x 32 outputs = 512, 2 per thread
    #pragma unroll
    for (int rep = 0; rep < 2; ++rep) {
        int node = (tid >> 5) + rep * 8;
        int c = tid & 31;
        int vv = blockIdx.x * 16 + node;
        if (vv < n) {
            float a = 0.f;
            #pragma unroll
            for (int k = 0; k < C1; ++k) a += srow[node][k] * sW[k * C2 + c];
            g2[(size_t)vv * C2 + c] = sdv[node] * a;
        }
    }
}

// ---------- layer-2 gather (float4 lanes: 8 nodes/wave, 32 nodes/block) ----------
__global__ __launch_bounds__(256) void gather2_k(const int* __restrict__ offsets,
                                                 const int* __restrict__ adj,
                                                 const float* __restrict__ dinv,
                                                 const float* __restrict__ g2,
                                                 const float* __restrict__ b2,
                                                 float* __restrict__ out, int n) {
    const int tid = threadIdx.x;
    const int wid = tid >> 6;
    const int l   = tid & 63;
    const int grp = l >> 3;                  // node-group within wave (0..7)
    const int lc  = l & 7;                   // lane within group
    const int v   = blockIdx.x * 32 + wid * 8 + grp;
    const int c0  = lc * 4;
    if (v >= n) return;

    float4 acc = *(const float4*)(g2 + (size_t)v * C2 + c0);   // self-loop term
    int start = offsets[v], end = offsets[v + 1];
    int j = start;
    for (; j + 4 <= end; j += 4) {
        int s0 = adj[j], s1 = adj[j + 1], s2 = adj[j + 2], s3 = adj[j + 3];
        float4 a0 = *(const float4*)(g2 + (size_t)s0 * C2 + c0);
        float4 a1 = *(const float4*)(g2 + (size_t)s1 * C2 + c0);
        float4 a2 = *(const float4*)(g2 + (size_t)s2 * C2 + c0);
        float4 a3 = *(const float4*)(g2 + (size_t)s3 * C2 + c0);
        acc.x += (a0.x + a1.x) + (a2.x + a3.x);
        acc.y += (a0.y + a1.y) + (a2.y + a3.y);
        acc.z += (a0.z + a1.z) + (a2.z + a3.z);
        acc.w += (a0.w + a1.w) + (a2.w + a3.w);
    }
    for (; j < end; ++j) {
        float4 a = *(const float4*)(g2 + (size_t)adj[j] * C2 + c0);
        acc.x += a.x; acc.y += a.y; acc.z += a.z; acc.w += a.w;
    }
    float dv = dinv[v];
    float4 bb = *(const float4*)(b2 + c0);
    float4 o = make_float4(bb.x + dv * acc.x, bb.y + dv * acc.y,
                           bb.z + dv * acc.z, bb.w + dv * acc.w);
    *(float4*)(out + (size_t)v * C2 + c0) = o;
}

extern "C" void kernel_launch(void* const* d_in, const int* in_sizes, int n_in,
                              void* d_out, int out_size, void* d_ws, size_t ws_size,
                              hipStream_t stream) {
    const float* x  = (const float*)d_in[0];
    const void*  ei = d_in[1];
    const float* W1 = (const float*)d_in[2];
    const float* b1 = (const float*)d_in[3];
    const float* W2 = (const float*)d_in[4];
    const float* b2 = (const float*)d_in[5];
    float* out = (float*)d_out;

    const int n = in_sizes[0] / K1;     // 100000
    const int E = in_sizes[1] / 2;      // 1600000

    // workspace layout (all 4-byte types)
    float* ws      = (float*)d_ws;
    int*   flag    = (int*)ws;                      // 16-float header
    float* dinv    = ws + 16;                       // n
    float* g1      = dinv + n;                      // n*64
    float* g2      = g1 + (size_t)n * C1;           // n*32
    int*   cnt     = (int*)(g2 + (size_t)n * C2);   // n
    int*   offsets = cnt + n;                       // n+1
    int*   cursor  = offsets + n + 1;               // n
    int*   partials= cursor + n;                    // 256 (padded)
    int*   adj     = partials + 256;                // E
    uintptr_t bp_a = ((uintptr_t)(adj + E) + 15) & ~(uintptr_t)15;
    unsigned short* Bp = (unsigned short*)bp_a;     // 192 KB packed W1 fragments

    const int nb_scan = (n + SCAN_ELEMS - 1) / SCAN_ELEMS;   // 49

    detect_k<<<1, 256, 0, stream>>>((const int*)ei, flag, in_sizes[1]);
    zero_k<<<(n + 255) / 256, 256, 0, stream>>>(cnt, n);
    cnt_k<<<(E + 255) / 256, 256, 0, stream>>>(ei, flag, cnt, E);
    dinv_k<<<(n + 255) / 256, 256, 0, stream>>>(cnt, dinv, n);

    packW1_k<<<48, 256, 0, stream>>>(W1, Bp);
    gemm1_k<<<(n + 127) / 128, 256, 0, stream>>>(x, Bp, dinv, g1, n);

    scan1_k<<<nb_scan, SCAN_BS, 0, stream>>>(cnt, partials, n);
    scan2_k<<<1, 256, 0, stream>>>(partials, offsets + n, nb_scan);
    scan3_k<<<nb_scan, SCAN_BS, 0, stream>>>(cnt, partials, offsets, cursor, n);
    fill_k<<<(E + 255) / 256, 256, 0, stream>>>(ei, flag, cursor, adj, E);

    gather1_k<<<(n + 15) / 16, 256, 0, stream>>>(offsets, adj, dinv, g1, b1, W2, g2, n);
    gather2_k<<<(n + 31) / 32, 256, 0, stream>>>(offsets, adj, dinv, g2, b2, out, n);
}